// Round 1
// baseline (4601.415 us; speedup 1.0000x reference)
//
#include <hip/hip_runtime.h>
#include <hip/hip_bf16.h>

#define HID 64
#define DIN 128
#define NCLS 4

// ---------------- degree / norm precompute ----------------

__global__ __launch_bounds__(256) void deg_kernel(const float* __restrict__ ea,
                                                  const int* __restrict__ dst,
                                                  const float* __restrict__ We,
                                                  const float* __restrict__ be,
                                                  float* __restrict__ deg, int E) {
    int e = blockIdx.x * blockDim.x + threadIdx.x;
    if (e >= E) return;
    float ew = ea[e] * We[0] + be[0];
    atomicAdd(&deg[dst[e]], ew);
}

__global__ __launch_bounds__(256) void dinv_kernel(float* __restrict__ deg, int N) {
    int n = blockIdx.x * blockDim.x + threadIdx.x;
    if (n >= N) return;
    float d = deg[n] + 1.0f;              // self-loop weight 1.0
    deg[n] = rsqrtf(d);                    // deg >= 1 always
}

__global__ __launch_bounds__(256) void norm_kernel(const float* __restrict__ ea,
                                                   const int* __restrict__ src,
                                                   const int* __restrict__ dst,
                                                   const float* __restrict__ We,
                                                   const float* __restrict__ be,
                                                   const float* __restrict__ dinv,
                                                   float* __restrict__ norm, int E) {
    int e = blockIdx.x * blockDim.x + threadIdx.x;
    if (e >= E) return;
    float ew = ea[e] * We[0] + be[0];
    norm[e] = dinv[src[e]] * ew * dinv[dst[e]];
}

// ---------------- input projection: h = relu(x @ W_in + b_in) ----------------
// wave-per-node: lane c computes output col c; x[n][k] is wave-uniform (L1),
// W_in[k][c] coalesced 256B per k, 32KB total stays in cache.

__global__ __launch_bounds__(256) void inproj_kernel(const float* __restrict__ x,
                                                     const float* __restrict__ W,
                                                     const float* __restrict__ b,
                                                     float* __restrict__ h, int N) {
    int t = blockIdx.x * blockDim.x + threadIdx.x;
    int n = t >> 6, c = t & 63;
    if (n >= N) return;
    const float* xr = x + (long)n * DIN;
    float acc = b[c];
#pragma unroll 8
    for (int k = 0; k < DIN; ++k)
        acc = fmaf(xr[k], W[k * HID + c], acc);
    h[t] = fmaxf(acc, 0.0f);
}

// ---------------- per-layer matmul: hw = h @ Wg ; agg init = hw*self_norm + bg ----------------

__global__ __launch_bounds__(256) void hw_kernel(const float* __restrict__ h,
                                                 const float* __restrict__ Wg,
                                                 const float* __restrict__ bg,
                                                 const float* __restrict__ dinv,
                                                 float* __restrict__ hw,
                                                 float* __restrict__ agg, int N) {
    int t = blockIdx.x * blockDim.x + threadIdx.x;
    int n = t >> 6, c = t & 63;
    if (n >= N) return;
    const float* hr = h + (long)n * HID;
    float acc = 0.0f;
#pragma unroll
    for (int k = 0; k < HID; ++k)
        acc = fmaf(hr[k], Wg[k * HID + c], acc);
    hw[t] = acc;
    float dn = dinv[n];
    agg[t] = acc * dn * dn + bg[c];       // self-loop term + bias folded in
}

// ---------------- edge scatter: agg[dst] += hw[src] * norm ----------------
// thread = (edge, 4-col group); 4 edges/wave, gathers & atomics both 256B/edge.

__global__ __launch_bounds__(256) void scatter_kernel(const int* __restrict__ src,
                                                      const int* __restrict__ dst,
                                                      const float* __restrict__ norm,
                                                      const float* __restrict__ hw,
                                                      float* __restrict__ agg, int E) {
    int t = blockIdx.x * blockDim.x + threadIdx.x;
    int e = t >> 4, cg = t & 15;
    if (e >= E) return;
    float nm = norm[e];
    int s = src[e], d = dst[e];
    const float4 v = *(const float4*)(hw + (long)s * HID + cg * 4);
    float* ap = agg + (long)d * HID + cg * 4;
    atomicAdd(ap + 0, v.x * nm);
    atomicAdd(ap + 1, v.y * nm);
    atomicAdd(ap + 2, v.z * nm);
    atomicAdd(ap + 3, v.w * nm);
}

// ---------------- layernorm + relu + optional residual (wave-per-node) ----------------

__global__ __launch_bounds__(256) void ln_kernel(const float* __restrict__ agg,
                                                 float* __restrict__ h,
                                                 int add_residual, int N) {
    int t = blockIdx.x * blockDim.x + threadIdx.x;
    int n = t >> 6;
    if (n >= N) return;
    float v = agg[t];
    float s = v, s2 = v * v;
#pragma unroll
    for (int off = 32; off; off >>= 1) {
        s  += __shfl_xor(s,  off);
        s2 += __shfl_xor(s2, off);
    }
    float mean = s * (1.0f / 64.0f);
    float var  = s2 * (1.0f / 64.0f) - mean * mean;
    float o = (v - mean) * rsqrtf(var + 1e-5f);
    o = fmaxf(o, 0.0f);
    if (add_residual) o += h[t];
    h[t] = o;
}

// ---------------- fused heads: attn + classifier ----------------
// wave-per-node (4 nodes/block). lane l holds h[l]; row staged in LDS.

__global__ __launch_bounds__(256) void head_kernel(const float* __restrict__ h,
                                                   const float* __restrict__ Wa1,
                                                   const float* __restrict__ ba1,
                                                   const float* __restrict__ Wa2,
                                                   const float* __restrict__ ba2,
                                                   const float* __restrict__ Wc1,
                                                   const float* __restrict__ bc1,
                                                   const float* __restrict__ Wc2,
                                                   const float* __restrict__ bc2,
                                                   float* __restrict__ out, int N) {
    __shared__ float hs[4][HID];
    __shared__ float cs[4][32];
    int t = blockIdx.x * blockDim.x + threadIdx.x;
    int n = t >> 6, lane = t & 63, w = threadIdx.x >> 6;
    bool valid = (n < N);
    float hv = valid ? h[(long)n * HID + lane] : 0.0f;
    hs[w][lane] = hv;
    __syncthreads();
    // a1 = relu(h @ Wa1 + ba1) for lanes 0..31, pre-multiplied by Wa2
    float z = 0.0f;
    if (lane < 32) {
        float a1 = ba1[lane];
#pragma unroll 8
        for (int k = 0; k < HID; ++k)
            a1 = fmaf(hs[w][k], Wa1[k * 32 + lane], a1);
        a1 = fmaxf(a1, 0.0f);
        z = a1 * Wa2[lane];
    }
#pragma unroll
    for (int off = 16; off; off >>= 1) z += __shfl_xor(z, off);
    float zsum = __shfl(z, 0);            // broadcast to all 64 lanes
    float attn = 1.0f / (1.0f + expf(-(zsum + ba2[0])));
    __syncthreads();
    hs[w][lane] = hv * attn;              // hh = h * attn
    __syncthreads();
    float c1 = 0.0f;
    if (lane < 32) {
        c1 = bc1[lane];
#pragma unroll 8
        for (int k = 0; k < HID; ++k)
            c1 = fmaf(hs[w][k], Wc1[k * 32 + lane], c1);
        cs[w][lane] = fmaxf(c1, 0.0f);
    }
    __syncthreads();
    if (valid && lane < NCLS) {
        float acc = bc2[lane];
#pragma unroll
        for (int j = 0; j < 32; ++j)
            acc = fmaf(cs[w][j], Wc2[j * NCLS + lane], acc);
        out[(long)n * NCLS + lane] = acc;
    }
    if (valid && lane == 0) out[(long)N * NCLS + n] = attn;
}

// ---------------- launcher ----------------

extern "C" void kernel_launch(void* const* d_in, const int* in_sizes, int n_in,
                              void* d_out, int out_size, void* d_ws, size_t ws_size,
                              hipStream_t stream) {
    const float* x    = (const float*)d_in[0];
    const float* ea   = (const float*)d_in[1];
    const int*   ei   = (const int*)d_in[2];
    const float* We   = (const float*)d_in[3];
    const float* be   = (const float*)d_in[4];
    const float* W_in = (const float*)d_in[5];
    const float* b_in = (const float*)d_in[6];
    const float* W_g  = (const float*)d_in[7];
    const float* b_g  = (const float*)d_in[8];
    const float* Wa1  = (const float*)d_in[9];
    const float* ba1  = (const float*)d_in[10];
    const float* Wa2  = (const float*)d_in[11];
    const float* ba2  = (const float*)d_in[12];
    const float* Wc1  = (const float*)d_in[13];
    const float* bc1  = (const float*)d_in[14];
    const float* Wc2  = (const float*)d_in[15];
    const float* bc2  = (const float*)d_in[16];
    float* out = (float*)d_out;

    const int N = in_sizes[0] / DIN;       // 100000
    const int E = in_sizes[1];             // 1600000
    const int* srcI = ei;
    const int* dstI = ei + E;

    float* ws   = (float*)d_ws;
    float* dinv = ws;                      // N  (deg during accumulation)
    float* norm = dinv + N;                // E
    float* h    = norm + E;                // N*HID
    float* hw   = h    + (long)N * HID;    // N*HID
    float* agg  = hw   + (long)N * HID;    // N*HID

    hipMemsetAsync(dinv, 0, N * sizeof(float), stream);

    deg_kernel <<<(E + 255) / 256, 256, 0, stream>>>(ea, dstI, We, be, dinv, E);
    dinv_kernel<<<(N + 255) / 256, 256, 0, stream>>>(dinv, N);
    norm_kernel<<<(E + 255) / 256, 256, 0, stream>>>(ea, srcI, dstI, We, be, dinv, norm, E);

    long nt = (long)N * HID;
    inproj_kernel<<<(nt + 255) / 256, 256, 0, stream>>>(x, W_in, b_in, h, N);

    for (int i = 0; i < 3; ++i) {
        hw_kernel<<<(nt + 255) / 256, 256, 0, stream>>>(h, W_g + i * HID * HID,
                                                        b_g + i * HID, dinv, hw, agg, N);
        long st = (long)E * 16;
        scatter_kernel<<<(st + 255) / 256, 256, 0, stream>>>(srcI, dstI, norm, hw, agg, E);
        ln_kernel<<<(nt + 255) / 256, 256, 0, stream>>>(agg, h, i > 0, N);
    }

    head_kernel<<<(nt + 255) / 256, 256, 0, stream>>>(h, Wa1, ba1, Wa2, ba2,
                                                      Wc1, bc1, Wc2, bc2, out, N);
}

// Round 2
// 1279.897 us; speedup vs baseline: 3.5951x; 3.5951x over previous
//
#include <hip/hip_runtime.h>
#include <hip/hip_bf16.h>

#define HID 64
#define DIN 128
#define NCLS 4

// ============ CSR build: degree/count, scan, fill ============

__global__ __launch_bounds__(256) void degcnt_kernel(const float* __restrict__ ea,
                                                     const int* __restrict__ dst,
                                                     const float* __restrict__ We,
                                                     const float* __restrict__ be,
                                                     float* __restrict__ deg,
                                                     int* __restrict__ cnt, int E) {
    int e = blockIdx.x * blockDim.x + threadIdx.x;
    if (e >= E) return;
    float ew = ea[e] * We[0] + be[0];
    int d = dst[e];
    atomicAdd(&deg[d], ew);
    atomicAdd(&cnt[d], 1);
}

__global__ __launch_bounds__(256) void dinv_kernel(float* __restrict__ deg, int N) {
    int n = blockIdx.x * blockDim.x + threadIdx.x;
    if (n >= N) return;
    deg[n] = rsqrtf(deg[n] + 1.0f);       // self-loop weight 1.0, deg >= 1
}

// inclusive scan of cnt per 256-block; block totals to bsum
__global__ __launch_bounds__(256) void scan1_kernel(const int* __restrict__ cnt,
                                                    int* __restrict__ scanned,
                                                    int* __restrict__ bsum, int N) {
    int t = blockIdx.x * 256 + threadIdx.x;
    int lane = threadIdx.x & 63, w = threadIdx.x >> 6;
    int x = (t < N) ? cnt[t] : 0;
#pragma unroll
    for (int off = 1; off < 64; off <<= 1) {
        int y = __shfl_up(x, off);
        if (lane >= off) x += y;
    }
    __shared__ int ws_[4];
    if (lane == 63) ws_[w] = x;
    __syncthreads();
    for (int i = 0; i < w; ++i) x += ws_[i];
    if (t < N) scanned[t] = x;
    if (threadIdx.x == 255) bsum[blockIdx.x] = x;
}

// single-block inclusive scan of block sums (nb <= 1024)
__global__ __launch_bounds__(1024) void scan2_kernel(int* __restrict__ bsum, int nb) {
    int t = threadIdx.x, lane = t & 63, w = t >> 6;
    int x = (t < nb) ? bsum[t] : 0;
#pragma unroll
    for (int off = 1; off < 64; off <<= 1) {
        int y = __shfl_up(x, off);
        if (lane >= off) x += y;
    }
    __shared__ int s16[16];
    if (lane == 63) s16[w] = x;
    __syncthreads();
    if (w == 0) {
        int y = (lane < 16) ? s16[lane] : 0;
#pragma unroll
        for (int off = 1; off < 16; off <<= 1) {
            int z = __shfl_up(y, off);
            if (lane >= off) y += z;
        }
        if (lane < 16) s16[lane] = y;
    }
    __syncthreads();
    if (w > 0) x += s16[w - 1];
    if (t < nb) bsum[t] = x;
}

// finalize: rowptr (N+1), fillpos (exclusive start)
__global__ __launch_bounds__(256) void scan3_kernel(const int* __restrict__ scanned,
                                                    const int* __restrict__ bsum,
                                                    const int* __restrict__ cnt,
                                                    int* __restrict__ rowptr,
                                                    int* __restrict__ fillpos, int N) {
    int t = blockIdx.x * 256 + threadIdx.x;
    if (t >= N) return;
    int add = (blockIdx.x > 0) ? bsum[blockIdx.x - 1] : 0;
    int incl = scanned[t] + add;
    rowptr[t + 1] = incl;
    fillpos[t] = incl - cnt[t];
    if (t == 0) rowptr[0] = 0;
}

// bucket-fill: srcnorm[p] = {src, dinv[src]*ew*dinv[dst]}
__global__ __launch_bounds__(256) void fill_kernel(const float* __restrict__ ea,
                                                   const int* __restrict__ src,
                                                   const int* __restrict__ dst,
                                                   const float* __restrict__ We,
                                                   const float* __restrict__ be,
                                                   const float* __restrict__ dinv,
                                                   int* __restrict__ fillpos,
                                                   float2* __restrict__ srcnorm, int E) {
    int e = blockIdx.x * blockDim.x + threadIdx.x;
    if (e >= E) return;
    float ew = ea[e] * We[0] + be[0];
    int s = src[e], d = dst[e];
    float nm = dinv[s] * ew * dinv[d];
    int p = atomicAdd(&fillpos[d], 1);
    srcnorm[p] = make_float2(__int_as_float(s), nm);
}

// ============ dense parts ============

__global__ __launch_bounds__(256) void inproj_kernel(const float* __restrict__ x,
                                                     const float* __restrict__ W,
                                                     const float* __restrict__ b,
                                                     float* __restrict__ h, int N) {
    int t = blockIdx.x * blockDim.x + threadIdx.x;
    int n = t >> 6, c = t & 63;
    if (n >= N) return;
    const float* xr = x + (long)n * DIN;
    float acc = b[c];
#pragma unroll 8
    for (int k = 0; k < DIN; ++k)
        acc = fmaf(xr[k], W[k * HID + c], acc);
    h[t] = fmaxf(acc, 0.0f);
}

__global__ __launch_bounds__(256) void hw_kernel(const float* __restrict__ h,
                                                 const float* __restrict__ Wg,
                                                 float* __restrict__ hw, int N) {
    int t = blockIdx.x * blockDim.x + threadIdx.x;
    int n = t >> 6, c = t & 63;
    if (n >= N) return;
    const float* hr = h + (long)n * HID;
    float acc = 0.0f;
#pragma unroll
    for (int k = 0; k < HID; ++k)
        acc = fmaf(hr[k], Wg[k * HID + c], acc);
    hw[t] = acc;
}

// ============ fused gather + self-term + bias + LN + ReLU + residual ============
// wave-per-node: lane c owns col c; loop over CSR in-edges, coalesced 256B
// gathers of hw[src]. No atomics.

__global__ __launch_bounds__(256) void gather_ln_kernel(const int* __restrict__ rowptr,
                                                        const float2* __restrict__ srcnorm,
                                                        const float* __restrict__ hw,
                                                        const float* __restrict__ dinv,
                                                        const float* __restrict__ bg,
                                                        float* __restrict__ h,
                                                        int add_residual, int N) {
    int t = blockIdx.x * blockDim.x + threadIdx.x;
    int n = t >> 6, c = t & 63;
    if (n >= N) return;
    float dn = dinv[n];
    float acc = fmaf(hw[t], dn * dn, bg[c]);
    int beg = rowptr[n], end = rowptr[n + 1];
    for (int i = beg; i < end; ++i) {
        float2 p = srcnorm[i];
        int s = __float_as_int(p.x);
        acc = fmaf(hw[((long)s << 6) | c], p.y, acc);
    }
    // layernorm over the 64 lanes
    float s1 = acc, s2 = acc * acc;
#pragma unroll
    for (int off = 32; off; off >>= 1) {
        s1 += __shfl_xor(s1, off);
        s2 += __shfl_xor(s2, off);
    }
    float mean = s1 * (1.0f / 64.0f);
    float var  = s2 * (1.0f / 64.0f) - mean * mean;
    float o = (acc - mean) * rsqrtf(var + 1e-5f);
    o = fmaxf(o, 0.0f);
    if (add_residual) o += h[t];
    h[t] = o;
}

// ============ fused heads ============

__global__ __launch_bounds__(256) void head_kernel(const float* __restrict__ h,
                                                   const float* __restrict__ Wa1,
                                                   const float* __restrict__ ba1,
                                                   const float* __restrict__ Wa2,
                                                   const float* __restrict__ ba2,
                                                   const float* __restrict__ Wc1,
                                                   const float* __restrict__ bc1,
                                                   const float* __restrict__ Wc2,
                                                   const float* __restrict__ bc2,
                                                   float* __restrict__ out, int N) {
    __shared__ float hs[4][HID];
    __shared__ float cs[4][32];
    int t = blockIdx.x * blockDim.x + threadIdx.x;
    int n = t >> 6, lane = t & 63, w = threadIdx.x >> 6;
    bool valid = (n < N);
    float hv = valid ? h[(long)n * HID + lane] : 0.0f;
    hs[w][lane] = hv;
    __syncthreads();
    float z = 0.0f;
    if (lane < 32) {
        float a1 = ba1[lane];
#pragma unroll 8
        for (int k = 0; k < HID; ++k)
            a1 = fmaf(hs[w][k], Wa1[k * 32 + lane], a1);
        a1 = fmaxf(a1, 0.0f);
        z = a1 * Wa2[lane];
    }
#pragma unroll
    for (int off = 16; off; off >>= 1) z += __shfl_xor(z, off);
    float zsum = __shfl(z, 0);
    float attn = 1.0f / (1.0f + expf(-(zsum + ba2[0])));
    __syncthreads();
    hs[w][lane] = hv * attn;
    __syncthreads();
    if (lane < 32) {
        float c1 = bc1[lane];
#pragma unroll 8
        for (int k = 0; k < HID; ++k)
            c1 = fmaf(hs[w][k], Wc1[k * 32 + lane], c1);
        cs[w][lane] = fmaxf(c1, 0.0f);
    }
    __syncthreads();
    if (valid && lane < NCLS) {
        float acc = bc2[lane];
#pragma unroll
        for (int j = 0; j < 32; ++j)
            acc = fmaf(cs[w][j], Wc2[j * NCLS + lane], acc);
        out[(long)n * NCLS + lane] = acc;
    }
    if (valid && lane == 0) out[(long)N * NCLS + n] = attn;
}

// ============ launcher ============

extern "C" void kernel_launch(void* const* d_in, const int* in_sizes, int n_in,
                              void* d_out, int out_size, void* d_ws, size_t ws_size,
                              hipStream_t stream) {
    const float* x    = (const float*)d_in[0];
    const float* ea   = (const float*)d_in[1];
    const int*   ei   = (const int*)d_in[2];
    const float* We   = (const float*)d_in[3];
    const float* be   = (const float*)d_in[4];
    const float* W_in = (const float*)d_in[5];
    const float* b_in = (const float*)d_in[6];
    const float* W_g  = (const float*)d_in[7];
    const float* b_g  = (const float*)d_in[8];
    const float* Wa1  = (const float*)d_in[9];
    const float* ba1  = (const float*)d_in[10];
    const float* Wa2  = (const float*)d_in[11];
    const float* ba2  = (const float*)d_in[12];
    const float* Wc1  = (const float*)d_in[13];
    const float* bc1  = (const float*)d_in[14];
    const float* Wc2  = (const float*)d_in[15];
    const float* bc2  = (const float*)d_in[16];
    float* out = (float*)d_out;

    const int N = in_sizes[0] / DIN;       // 100000
    const int E = in_sizes[1];             // 1600000
    const int* srcI = ei;
    const int* dstI = ei + E;
    const int nblk = (N + 255) / 256;      // scan blocks (<=1024 required)

    // workspace layout (floats/ints, all offsets 8B-aligned: N, E, N*64 all even)
    float*  ws      = (float*)d_ws;
    float*  dinv    = ws;                        // N floats (deg during accum)
    float*  h       = dinv + N;                  // N*64
    float*  hw      = h + (long)N * HID;         // N*64
    float2* srcnorm = (float2*)(hw + (long)N * HID);  // E float2
    int*    cnt     = (int*)(srcnorm + E);       // N
    int*    scanned = cnt + N;                   // N
    int*    bsum    = scanned + N;               // 1024
    int*    rowptr  = bsum + 1024;               // N+1
    int*    fillpos = rowptr + N + 1;            // N

    hipMemsetAsync(dinv, 0, N * sizeof(float), stream);
    hipMemsetAsync(cnt,  0, N * sizeof(int), stream);

    degcnt_kernel<<<(E + 255) / 256, 256, 0, stream>>>(ea, dstI, We, be, dinv, cnt, E);
    dinv_kernel  <<<nblk, 256, 0, stream>>>(dinv, N);
    scan1_kernel <<<nblk, 256, 0, stream>>>(cnt, scanned, bsum, N);
    scan2_kernel <<<1, 1024, 0, stream>>>(bsum, nblk);
    scan3_kernel <<<nblk, 256, 0, stream>>>(scanned, bsum, cnt, rowptr, fillpos, N);
    fill_kernel  <<<(E + 255) / 256, 256, 0, stream>>>(ea, srcI, dstI, We, be, dinv,
                                                       fillpos, srcnorm, E);

    long nt = (long)N * HID;
    inproj_kernel<<<(nt + 255) / 256, 256, 0, stream>>>(x, W_in, b_in, h, N);

    for (int i = 0; i < 3; ++i) {
        hw_kernel<<<(nt + 255) / 256, 256, 0, stream>>>(h, W_g + i * HID * HID, hw, N);
        gather_ln_kernel<<<(nt + 255) / 256, 256, 0, stream>>>(rowptr, srcnorm, hw, dinv,
                                                               b_g + i * HID, h, i > 0, N);
    }

    head_kernel<<<(nt + 255) / 256, 256, 0, stream>>>(h, Wa1, ba1, Wa2, ba2,
                                                      Wc1, bc1, Wc2, bc2, out, N);
}

// Round 3
// 743.135 us; speedup vs baseline: 6.1919x; 1.7223x over previous
//
#include <hip/hip_runtime.h>
#include <hip/hip_bf16.h>

#define HID 64
#define DIN 128
#define NCLS 4

__device__ __forceinline__ float bcast(float v, int l) {
    return __uint_as_float(__builtin_amdgcn_readlane(__float_as_uint(v), l));
}

// ============ CSR build: degree/count, scan, fill ============

__global__ __launch_bounds__(256) void degcnt_kernel(const float* __restrict__ ea,
                                                     const int* __restrict__ dst,
                                                     const float* __restrict__ We,
                                                     const float* __restrict__ be,
                                                     float* __restrict__ deg,
                                                     int* __restrict__ cnt, int E) {
    int e = blockIdx.x * blockDim.x + threadIdx.x;
    if (e >= E) return;
    float ew = ea[e] * We[0] + be[0];
    int d = dst[e];
    atomicAdd(&deg[d], ew);
    atomicAdd(&cnt[d], 1);
}

__global__ __launch_bounds__(256) void dinv_kernel(float* __restrict__ deg, int N) {
    int n = blockIdx.x * blockDim.x + threadIdx.x;
    if (n >= N) return;
    deg[n] = rsqrtf(deg[n] + 1.0f);       // self-loop weight 1.0, deg >= 1
}

__global__ __launch_bounds__(256) void scan1_kernel(const int* __restrict__ cnt,
                                                    int* __restrict__ scanned,
                                                    int* __restrict__ bsum, int N) {
    int t = blockIdx.x * 256 + threadIdx.x;
    int lane = threadIdx.x & 63, w = threadIdx.x >> 6;
    int x = (t < N) ? cnt[t] : 0;
#pragma unroll
    for (int off = 1; off < 64; off <<= 1) {
        int y = __shfl_up(x, off);
        if (lane >= off) x += y;
    }
    __shared__ int ws_[4];
    if (lane == 63) ws_[w] = x;
    __syncthreads();
    for (int i = 0; i < w; ++i) x += ws_[i];
    if (t < N) scanned[t] = x;
    if (threadIdx.x == 255) bsum[blockIdx.x] = x;
}

__global__ __launch_bounds__(1024) void scan2_kernel(int* __restrict__ bsum, int nb) {
    int t = threadIdx.x, lane = t & 63, w = t >> 6;
    int x = (t < nb) ? bsum[t] : 0;
#pragma unroll
    for (int off = 1; off < 64; off <<= 1) {
        int y = __shfl_up(x, off);
        if (lane >= off) x += y;
    }
    __shared__ int s16[16];
    if (lane == 63) s16[w] = x;
    __syncthreads();
    if (w == 0) {
        int y = (lane < 16) ? s16[lane] : 0;
#pragma unroll
        for (int off = 1; off < 16; off <<= 1) {
            int z = __shfl_up(y, off);
            if (lane >= off) y += z;
        }
        if (lane < 16) s16[lane] = y;
    }
    __syncthreads();
    if (w > 0) x += s16[w - 1];
    if (t < nb) bsum[t] = x;
}

__global__ __launch_bounds__(256) void scan3_kernel(const int* __restrict__ scanned,
                                                    const int* __restrict__ bsum,
                                                    const int* __restrict__ cnt,
                                                    int* __restrict__ rowptr,
                                                    int* __restrict__ fillpos, int N) {
    int t = blockIdx.x * 256 + threadIdx.x;
    if (t >= N) return;
    int add = (blockIdx.x > 0) ? bsum[blockIdx.x - 1] : 0;
    int incl = scanned[t] + add;
    rowptr[t + 1] = incl;
    fillpos[t] = incl - cnt[t];
    if (t == 0) rowptr[0] = 0;
}

__global__ __launch_bounds__(256) void fill_kernel(const float* __restrict__ ea,
                                                   const int* __restrict__ src,
                                                   const int* __restrict__ dst,
                                                   const float* __restrict__ We,
                                                   const float* __restrict__ be,
                                                   const float* __restrict__ dinv,
                                                   int* __restrict__ fillpos,
                                                   float2* __restrict__ srcnorm, int E) {
    int e = blockIdx.x * blockDim.x + threadIdx.x;
    if (e >= E) return;
    float ew = ea[e] * We[0] + be[0];
    int s = src[e], d = dst[e];
    float nm = dinv[s] * ew * dinv[d];
    int p = atomicAdd(&fillpos[d], 1);
    srcnorm[p] = make_float2(__int_as_float(s), nm);
}

// ============ input proj: 4 nodes/wave, readlane broadcast, ILP-4 ============

__global__ __launch_bounds__(256) void inproj_kernel(const float* __restrict__ x,
                                                     const float* __restrict__ W,
                                                     const float* __restrict__ b,
                                                     float* __restrict__ h, int N) {
    int lane = threadIdx.x & 63;
    int gw = (blockIdx.x * 256 + threadIdx.x) >> 6;   // global wave id
    int n0 = gw * 4;
    if (n0 >= N) return;
    float bc = b[lane];
    float xl[4], xh[4], acc[4];
#pragma unroll
    for (int j = 0; j < 4; ++j) {
        int n = n0 + j; if (n >= N) n = N - 1;
        xl[j] = x[(long)n * DIN + lane];
        xh[j] = x[(long)n * DIN + 64 + lane];
        acc[j] = bc;
    }
#pragma unroll
    for (int k = 0; k < 64; ++k) {
        float wv = W[k * HID + lane];
#pragma unroll
        for (int j = 0; j < 4; ++j)
            acc[j] = fmaf(bcast(xl[j], k), wv, acc[j]);
    }
#pragma unroll
    for (int k = 0; k < 64; ++k) {
        float wv = W[(64 + k) * HID + lane];
#pragma unroll
        for (int j = 0; j < 4; ++j)
            acc[j] = fmaf(bcast(xh[j], k), wv, acc[j]);
    }
#pragma unroll
    for (int j = 0; j < 4; ++j)
        if (n0 + j < N) h[(long)(n0 + j) * HID + lane] = fmaxf(acc[j], 0.0f);
}

// ============ hw = h @ Wg : W column in 64 VGPRs, grid-stride, 4 nodes/iter ============

__global__ __launch_bounds__(256) void hw_kernel(const float* __restrict__ h,
                                                 const float* __restrict__ Wg,
                                                 float* __restrict__ hw, int N) {
    int lane = threadIdx.x & 63;
    int gw = (blockIdx.x * 256 + threadIdx.x) >> 6;
    int nw = (gridDim.x * 256) >> 6;
    float wcol[64];
#pragma unroll
    for (int k = 0; k < 64; ++k) wcol[k] = Wg[k * HID + lane];
    for (int n0 = gw * 4; n0 < N; n0 += nw * 4) {
        float hv[4], acc[4];
#pragma unroll
        for (int j = 0; j < 4; ++j) {
            int n = n0 + j; if (n >= N) n = N - 1;
            hv[j] = h[((long)n << 6) | lane];
            acc[j] = 0.0f;
        }
#pragma unroll
        for (int k = 0; k < 64; ++k) {
#pragma unroll
            for (int j = 0; j < 4; ++j)
                acc[j] = fmaf(bcast(hv[j], k), wcol[k], acc[j]);
        }
#pragma unroll
        for (int j = 0; j < 4; ++j)
            if (n0 + j < N) hw[((long)(n0 + j) << 6) | lane] = acc[j];
    }
}

// ============ fused gather + self + bias + LN + ReLU + residual ============

__global__ __launch_bounds__(256) void gather_ln_kernel(const int* __restrict__ rowptr,
                                                        const float2* __restrict__ srcnorm,
                                                        const float* __restrict__ hw,
                                                        const float* __restrict__ dinv,
                                                        const float* __restrict__ bg,
                                                        float* __restrict__ h,
                                                        int add_residual, int N) {
    int t = blockIdx.x * blockDim.x + threadIdx.x;
    int n = t >> 6, c = t & 63;
    if (n >= N) return;
    float dn = dinv[n];
    float acc = fmaf(hw[t], dn * dn, bg[c]);
    int beg = rowptr[n], end = rowptr[n + 1];
    int i = beg;
    int end4 = beg + ((end - beg) & ~3);
    for (; i < end4; i += 4) {
        float2 p0 = srcnorm[i], p1 = srcnorm[i + 1], p2 = srcnorm[i + 2], p3 = srcnorm[i + 3];
        float v0 = hw[((long)__float_as_int(p0.x) << 6) | c];
        float v1 = hw[((long)__float_as_int(p1.x) << 6) | c];
        float v2 = hw[((long)__float_as_int(p2.x) << 6) | c];
        float v3 = hw[((long)__float_as_int(p3.x) << 6) | c];
        acc = fmaf(v0, p0.y, acc);
        acc = fmaf(v1, p1.y, acc);
        acc = fmaf(v2, p2.y, acc);
        acc = fmaf(v3, p3.y, acc);
    }
    for (; i < end; ++i) {
        float2 p = srcnorm[i];
        acc = fmaf(hw[((long)__float_as_int(p.x) << 6) | c], p.y, acc);
    }
    float s1 = acc, s2 = acc * acc;
#pragma unroll
    for (int off = 32; off; off >>= 1) {
        s1 += __shfl_xor(s1, off);
        s2 += __shfl_xor(s2, off);
    }
    float mean = s1 * (1.0f / 64.0f);
    float var  = s2 * (1.0f / 64.0f) - mean * mean;
    float o = (acc - mean) * rsqrtf(var + 1e-5f);
    o = fmaxf(o, 0.0f);
    if (add_residual) o += h[t];
    h[t] = o;
}

// ============ fused heads: split-k, no block syncs ============

__global__ __launch_bounds__(256) void head_kernel(const float* __restrict__ h,
                                                   const float* __restrict__ Wa1,
                                                   const float* __restrict__ ba1,
                                                   const float* __restrict__ Wa2,
                                                   const float* __restrict__ ba2,
                                                   const float* __restrict__ Wc1,
                                                   const float* __restrict__ bc1,
                                                   const float* __restrict__ Wc2,
                                                   const float* __restrict__ bc2,
                                                   float* __restrict__ out, int N) {
    __shared__ float hs[4][HID];
    __shared__ float cs[4][32];
    int t = blockIdx.x * blockDim.x + threadIdx.x;
    int n = t >> 6, lane = t & 63, w = threadIdx.x >> 6;
    if (n >= N) return;                    // whole wave uniform (n per wave)
    int jj = lane & 31, hf = lane >> 5;
    float hv = h[((long)n << 6) | lane];
    hs[w][lane] = hv;                      // wave-private LDS row: no __syncthreads
    // a1[jj] = relu(h @ Wa1 + ba1); split-k across the two 32-lane halves
    float a1p = 0.0f;
#pragma unroll
    for (int k = 0; k < 32; ++k) {
        int kk = hf * 32 + k;
        a1p = fmaf(hs[w][kk], Wa1[kk * 32 + jj], a1p);
    }
    a1p += __shfl_xor(a1p, 32);
    float a1 = fmaxf(a1p + ba1[jj], 0.0f);
    float z = a1 * Wa2[jj];
#pragma unroll
    for (int off = 16; off; off >>= 1) z += __shfl_xor(z, off);
    float attn = 1.0f / (1.0f + expf(-(z + ba2[0])));
    hs[w][lane] = hv * attn;
    // c1[jj] = relu((h*attn) @ Wc1 + bc1); split-k
    float c1p = 0.0f;
#pragma unroll
    for (int k = 0; k < 32; ++k) {
        int kk = hf * 32 + k;
        c1p = fmaf(hs[w][kk], Wc1[kk * 32 + jj], c1p);
    }
    c1p += __shfl_xor(c1p, 32);
    if (hf == 0) cs[w][jj] = fmaxf(c1p + bc1[jj], 0.0f);
    if (lane < NCLS) {
        float acc = bc2[lane];
#pragma unroll
        for (int j = 0; j < 32; ++j)
            acc = fmaf(cs[w][j], Wc2[j * NCLS + lane], acc);
        out[(long)n * NCLS + lane] = acc;
    }
    if (lane == 0) out[(long)N * NCLS + n] = attn;
}

// ============ launcher ============

extern "C" void kernel_launch(void* const* d_in, const int* in_sizes, int n_in,
                              void* d_out, int out_size, void* d_ws, size_t ws_size,
                              hipStream_t stream) {
    const float* x    = (const float*)d_in[0];
    const float* ea   = (const float*)d_in[1];
    const int*   ei   = (const int*)d_in[2];
    const float* We   = (const float*)d_in[3];
    const float* be   = (const float*)d_in[4];
    const float* W_in = (const float*)d_in[5];
    const float* b_in = (const float*)d_in[6];
    const float* W_g  = (const float*)d_in[7];
    const float* b_g  = (const float*)d_in[8];
    const float* Wa1  = (const float*)d_in[9];
    const float* ba1  = (const float*)d_in[10];
    const float* Wa2  = (const float*)d_in[11];
    const float* ba2  = (const float*)d_in[12];
    const float* Wc1  = (const float*)d_in[13];
    const float* bc1  = (const float*)d_in[14];
    const float* Wc2  = (const float*)d_in[15];
    const float* bc2  = (const float*)d_in[16];
    float* out = (float*)d_out;

    const int N = in_sizes[0] / DIN;       // 100000
    const int E = in_sizes[1];             // 1600000
    const int* srcI = ei;
    const int* dstI = ei + E;
    const int nblk = (N + 255) / 256;      // scan blocks (<=1024 required)

    float*  ws      = (float*)d_ws;
    float*  dinv    = ws;                        // N floats (deg during accum)
    float*  h       = dinv + N;                  // N*64
    float*  hw      = h + (long)N * HID;         // N*64
    float2* srcnorm = (float2*)(hw + (long)N * HID);  // E float2
    int*    cnt     = (int*)(srcnorm + E);       // N
    int*    scanned = cnt + N;                   // N
    int*    bsum    = scanned + N;               // 1024
    int*    rowptr  = bsum + 1024;               // N+1
    int*    fillpos = rowptr + N + 1;            // N

    hipMemsetAsync(dinv, 0, N * sizeof(float), stream);
    hipMemsetAsync(cnt,  0, N * sizeof(int), stream);

    degcnt_kernel<<<(E + 255) / 256, 256, 0, stream>>>(ea, dstI, We, be, dinv, cnt, E);
    dinv_kernel  <<<nblk, 256, 0, stream>>>(dinv, N);
    scan1_kernel <<<nblk, 256, 0, stream>>>(cnt, scanned, bsum, N);
    scan2_kernel <<<1, 1024, 0, stream>>>(bsum, nblk);
    scan3_kernel <<<nblk, 256, 0, stream>>>(scanned, bsum, cnt, rowptr, fillpos, N);
    fill_kernel  <<<(E + 255) / 256, 256, 0, stream>>>(ea, srcI, dstI, We, be, dinv,
                                                       fillpos, srcnorm, E);

    long nt = (long)N * HID;
    // inproj: 4 waves/block, 4 nodes/wave -> 16 nodes/block
    inproj_kernel<<<(N + 15) / 16, 256, 0, stream>>>(x, W_in, b_in, h, N);

    for (int i = 0; i < 3; ++i) {
        hw_kernel<<<1024, 256, 0, stream>>>(h, W_g + i * HID * HID, hw, N);
        gather_ln_kernel<<<(nt + 255) / 256, 256, 0, stream>>>(rowptr, srcnorm, hw, dinv,
                                                               b_g + i * HID, h, i > 0, N);
    }

    head_kernel<<<(nt + 255) / 256, 256, 0, stream>>>(h, Wa1, ba1, Wa2, ba2,
                                                      Wc1, bc1, Wc2, bc2, out, N);
}

// Round 4
// 617.053 us; speedup vs baseline: 7.4571x; 1.2043x over previous
//
#include <hip/hip_runtime.h>
#include <hip/hip_bf16.h>

#define HID 64
#define DIN 128
#define NCLS 4

__device__ __forceinline__ float bcast(float v, int l) {
    return __uint_as_float(__builtin_amdgcn_readlane(__float_as_uint(v), l));
}

// ============ CSR build ============
// pk[d] packs {cnt:24 | deg_fixedpoint:40}, scale 2^20. One u64 atomic per
// edge; returned old value's high bits = this edge's rank in its bucket.

__global__ __launch_bounds__(256) void degrank_kernel(const float* __restrict__ ea,
                                                      const int* __restrict__ dst,
                                                      const float* __restrict__ We,
                                                      const float* __restrict__ be,
                                                      unsigned long long* __restrict__ pk,
                                                      int* __restrict__ rank, int E) {
    int e = blockIdx.x * blockDim.x + threadIdx.x;
    if (e >= E) return;
    float ew = ea[e] * We[0] + be[0];
    unsigned long long fx = (unsigned long long)(ew * 1048576.0f + 0.5f);
    unsigned long long old = atomicAdd(&pk[dst[e]], (1ull << 40) | fx);
    rank[e] = (int)(old >> 40);
}

__global__ __launch_bounds__(256) void unpack_kernel(const unsigned long long* __restrict__ pk,
                                                     float* __restrict__ dinv,
                                                     int* __restrict__ cnt, int N) {
    int n = blockIdx.x * blockDim.x + threadIdx.x;
    if (n >= N) return;
    unsigned long long v = pk[n];
    cnt[n] = (int)(v >> 40);
    float deg = (float)((double)(v & ((1ull << 40) - 1)) * (1.0 / 1048576.0));
    dinv[n] = rsqrtf(deg + 1.0f);          // self-loop weight 1.0, deg >= 0
}

__global__ __launch_bounds__(256) void scan1_kernel(const int* __restrict__ cnt,
                                                    int* __restrict__ scanned,
                                                    int* __restrict__ bsum, int N) {
    int t = blockIdx.x * 256 + threadIdx.x;
    int lane = threadIdx.x & 63, w = threadIdx.x >> 6;
    int x = (t < N) ? cnt[t] : 0;
#pragma unroll
    for (int off = 1; off < 64; off <<= 1) {
        int y = __shfl_up(x, off);
        if (lane >= off) x += y;
    }
    __shared__ int ws_[4];
    if (lane == 63) ws_[w] = x;
    __syncthreads();
    for (int i = 0; i < w; ++i) x += ws_[i];
    if (t < N) scanned[t] = x;
    if (threadIdx.x == 255) bsum[blockIdx.x] = x;
}

__global__ __launch_bounds__(1024) void scan2_kernel(int* __restrict__ bsum, int nb) {
    int t = threadIdx.x, lane = t & 63, w = t >> 6;
    int x = (t < nb) ? bsum[t] : 0;
#pragma unroll
    for (int off = 1; off < 64; off <<= 1) {
        int y = __shfl_up(x, off);
        if (lane >= off) x += y;
    }
    __shared__ int s16[16];
    if (lane == 63) s16[w] = x;
    __syncthreads();
    if (w == 0) {
        int y = (lane < 16) ? s16[lane] : 0;
#pragma unroll
        for (int off = 1; off < 16; off <<= 1) {
            int z = __shfl_up(y, off);
            if (lane >= off) y += z;
        }
        if (lane < 16) s16[lane] = y;
    }
    __syncthreads();
    if (w > 0) x += s16[w - 1];
    if (t < nb) bsum[t] = x;
}

__global__ __launch_bounds__(256) void scan3_kernel(const int* __restrict__ scanned,
                                                    const int* __restrict__ bsum,
                                                    int* __restrict__ rowptr, int N) {
    int t = blockIdx.x * 256 + threadIdx.x;
    if (t >= N) return;
    int add = (blockIdx.x > 0) ? bsum[blockIdx.x - 1] : 0;
    rowptr[t + 1] = scanned[t] + add;
    if (t == 0) rowptr[0] = 0;
}

// atomic-free fill: slot = rowptr[dst] + rank
__global__ __launch_bounds__(256) void fill_kernel(const float* __restrict__ ea,
                                                   const int* __restrict__ src,
                                                   const int* __restrict__ dst,
                                                   const int* __restrict__ rank,
                                                   const float* __restrict__ We,
                                                   const float* __restrict__ be,
                                                   const float* __restrict__ dinv,
                                                   const int* __restrict__ rowptr,
                                                   float2* __restrict__ srcnorm, int E) {
    int e = blockIdx.x * blockDim.x + threadIdx.x;
    if (e >= E) return;
    float ew = ea[e] * We[0] + be[0];
    int s = src[e], d = dst[e];
    float nm = dinv[s] * ew * dinv[d];
    int slot = rowptr[d] + rank[e];
    srcnorm[slot] = make_float2(__int_as_float(s), nm);
}

// ============ input proj: 4 nodes/wave, readlane broadcast, ILP-4 ============

__global__ __launch_bounds__(256) void inproj_kernel(const float* __restrict__ x,
                                                     const float* __restrict__ W,
                                                     const float* __restrict__ b,
                                                     float* __restrict__ h, int N) {
    int lane = threadIdx.x & 63;
    int gw = (blockIdx.x * 256 + threadIdx.x) >> 6;
    int n0 = gw * 4;
    if (n0 >= N) return;
    float bc = b[lane];
    float xl[4], xh[4], acc[4];
#pragma unroll
    for (int j = 0; j < 4; ++j) {
        int n = n0 + j; if (n >= N) n = N - 1;
        xl[j] = x[(long)n * DIN + lane];
        xh[j] = x[(long)n * DIN + 64 + lane];
        acc[j] = bc;
    }
#pragma unroll
    for (int k = 0; k < 64; ++k) {
        float wv = W[k * HID + lane];
#pragma unroll
        for (int j = 0; j < 4; ++j)
            acc[j] = fmaf(bcast(xl[j], k), wv, acc[j]);
    }
#pragma unroll
    for (int k = 0; k < 64; ++k) {
        float wv = W[(64 + k) * HID + lane];
#pragma unroll
        for (int j = 0; j < 4; ++j)
            acc[j] = fmaf(bcast(xh[j], k), wv, acc[j]);
    }
#pragma unroll
    for (int j = 0; j < 4; ++j)
        if (n0 + j < N) h[(long)(n0 + j) * HID + lane] = fmaxf(acc[j], 0.0f);
}

// ============ hw = h @ Wg : W column in 64 VGPRs, grid-stride, 4 nodes/iter ============

__global__ __launch_bounds__(256) void hw_kernel(const float* __restrict__ h,
                                                 const float* __restrict__ Wg,
                                                 float* __restrict__ hw, int N) {
    int lane = threadIdx.x & 63;
    int gw = (blockIdx.x * 256 + threadIdx.x) >> 6;
    int nw = (gridDim.x * 256) >> 6;
    float wcol[64];
#pragma unroll
    for (int k = 0; k < 64; ++k) wcol[k] = Wg[k * HID + lane];
    for (int n0 = gw * 4; n0 < N; n0 += nw * 4) {
        float hv[4], acc[4];
#pragma unroll
        for (int j = 0; j < 4; ++j) {
            int n = n0 + j; if (n >= N) n = N - 1;
            hv[j] = h[((long)n << 6) | lane];
            acc[j] = 0.0f;
        }
#pragma unroll
        for (int k = 0; k < 64; ++k) {
#pragma unroll
            for (int j = 0; j < 4; ++j)
                acc[j] = fmaf(bcast(hv[j], k), wcol[k], acc[j]);
        }
#pragma unroll
        for (int j = 0; j < 4; ++j)
            if (n0 + j < N) hw[((long)(n0 + j) << 6) | lane] = acc[j];
    }
}

// ============ fused gather + self + bias + LN + ReLU + residual ============

__global__ __launch_bounds__(256) void gather_ln_kernel(const int* __restrict__ rowptr,
                                                        const float2* __restrict__ srcnorm,
                                                        const float* __restrict__ hw,
                                                        const float* __restrict__ dinv,
                                                        const float* __restrict__ bg,
                                                        float* __restrict__ h,
                                                        int add_residual, int N) {
    int t = blockIdx.x * blockDim.x + threadIdx.x;
    int n = t >> 6, c = t & 63;
    if (n >= N) return;
    float dn = dinv[n];
    float acc = fmaf(hw[t], dn * dn, bg[c]);
    int beg = rowptr[n], end = rowptr[n + 1];
    int i = beg;
    int end4 = beg + ((end - beg) & ~3);
    for (; i < end4; i += 4) {
        float2 p0 = srcnorm[i], p1 = srcnorm[i + 1], p2 = srcnorm[i + 2], p3 = srcnorm[i + 3];
        float v0 = hw[((long)__float_as_int(p0.x) << 6) | c];
        float v1 = hw[((long)__float_as_int(p1.x) << 6) | c];
        float v2 = hw[((long)__float_as_int(p2.x) << 6) | c];
        float v3 = hw[((long)__float_as_int(p3.x) << 6) | c];
        acc = fmaf(v0, p0.y, acc);
        acc = fmaf(v1, p1.y, acc);
        acc = fmaf(v2, p2.y, acc);
        acc = fmaf(v3, p3.y, acc);
    }
    for (; i < end; ++i) {
        float2 p = srcnorm[i];
        acc = fmaf(hw[((long)__float_as_int(p.x) << 6) | c], p.y, acc);
    }
    float s1 = acc, s2 = acc * acc;
#pragma unroll
    for (int off = 32; off; off >>= 1) {
        s1 += __shfl_xor(s1, off);
        s2 += __shfl_xor(s2, off);
    }
    float mean = s1 * (1.0f / 64.0f);
    float var  = s2 * (1.0f / 64.0f) - mean * mean;
    float o = (acc - mean) * rsqrtf(var + 1e-5f);
    o = fmaxf(o, 0.0f);
    if (add_residual) o += h[t];
    h[t] = o;
}

// ============ fused heads: split-k, no block syncs ============

__global__ __launch_bounds__(256) void head_kernel(const float* __restrict__ h,
                                                   const float* __restrict__ Wa1,
                                                   const float* __restrict__ ba1,
                                                   const float* __restrict__ Wa2,
                                                   const float* __restrict__ ba2,
                                                   const float* __restrict__ Wc1,
                                                   const float* __restrict__ bc1,
                                                   const float* __restrict__ Wc2,
                                                   const float* __restrict__ bc2,
                                                   float* __restrict__ out, int N) {
    __shared__ float hs[4][HID];
    __shared__ float cs[4][32];
    int t = blockIdx.x * blockDim.x + threadIdx.x;
    int n = t >> 6, lane = t & 63, w = threadIdx.x >> 6;
    if (n >= N) return;
    int jj = lane & 31, hf = lane >> 5;
    float hv = h[((long)n << 6) | lane];
    hs[w][lane] = hv;
    float a1p = 0.0f;
#pragma unroll
    for (int k = 0; k < 32; ++k) {
        int kk = hf * 32 + k;
        a1p = fmaf(hs[w][kk], Wa1[kk * 32 + jj], a1p);
    }
    a1p += __shfl_xor(a1p, 32);
    float a1 = fmaxf(a1p + ba1[jj], 0.0f);
    float z = a1 * Wa2[jj];
#pragma unroll
    for (int off = 16; off; off >>= 1) z += __shfl_xor(z, off);
    float attn = 1.0f / (1.0f + expf(-(z + ba2[0])));
    hs[w][lane] = hv * attn;
    float c1p = 0.0f;
#pragma unroll
    for (int k = 0; k < 32; ++k) {
        int kk = hf * 32 + k;
        c1p = fmaf(hs[w][kk], Wc1[kk * 32 + jj], c1p);
    }
    c1p += __shfl_xor(c1p, 32);
    if (hf == 0) cs[w][jj] = fmaxf(c1p + bc1[jj], 0.0f);
    if (lane < NCLS) {
        float acc = bc2[lane];
#pragma unroll
        for (int j = 0; j < 32; ++j)
            acc = fmaf(cs[w][j], Wc2[j * NCLS + lane], acc);
        out[(long)n * NCLS + lane] = acc;
    }
    if (lane == 0) out[(long)N * NCLS + n] = attn;
}

// ============ launcher ============

extern "C" void kernel_launch(void* const* d_in, const int* in_sizes, int n_in,
                              void* d_out, int out_size, void* d_ws, size_t ws_size,
                              hipStream_t stream) {
    const float* x    = (const float*)d_in[0];
    const float* ea   = (const float*)d_in[1];
    const int*   ei   = (const int*)d_in[2];
    const float* We   = (const float*)d_in[3];
    const float* be   = (const float*)d_in[4];
    const float* W_in = (const float*)d_in[5];
    const float* b_in = (const float*)d_in[6];
    const float* W_g  = (const float*)d_in[7];
    const float* b_g  = (const float*)d_in[8];
    const float* Wa1  = (const float*)d_in[9];
    const float* ba1  = (const float*)d_in[10];
    const float* Wa2  = (const float*)d_in[11];
    const float* ba2  = (const float*)d_in[12];
    const float* Wc1  = (const float*)d_in[13];
    const float* bc1  = (const float*)d_in[14];
    const float* Wc2  = (const float*)d_in[15];
    const float* bc2  = (const float*)d_in[16];
    float* out = (float*)d_out;

    const int N = in_sizes[0] / DIN;       // 100000
    const int E = in_sizes[1];             // 1600000
    const int* srcI = ei;
    const int* dstI = ei + E;
    const int nblk = (N + 255) / 256;      // scan blocks (<=1024 required)

    // workspace layout (4B words; srcnorm offset is even -> 8B aligned)
    unsigned long long* pk = (unsigned long long*)d_ws;     // N u64
    float*  dinv    = (float*)(pk + N);                     // N
    float*  h       = dinv + N;                             // N*64
    float*  hw      = h + (long)N * HID;                    // N*64
    float2* srcnorm = (float2*)(hw + (long)N * HID);        // E float2
    int*    cnt     = (int*)(srcnorm + E);                  // N
    int*    scanned = cnt + N;                              // N
    int*    bsum    = scanned + N;                          // 1024
    int*    rowptr  = bsum + 1024;                          // N+1
    int*    rank    = rowptr + N + 1;                       // E

    hipMemsetAsync(pk, 0, N * sizeof(unsigned long long), stream);

    degrank_kernel<<<(E + 255) / 256, 256, 0, stream>>>(ea, dstI, We, be, pk, rank, E);
    unpack_kernel <<<nblk, 256, 0, stream>>>(pk, dinv, cnt, N);
    scan1_kernel  <<<nblk, 256, 0, stream>>>(cnt, scanned, bsum, N);
    scan2_kernel  <<<1, 1024, 0, stream>>>(bsum, nblk);
    scan3_kernel  <<<nblk, 256, 0, stream>>>(scanned, bsum, rowptr, N);
    fill_kernel   <<<(E + 255) / 256, 256, 0, stream>>>(ea, srcI, dstI, rank, We, be,
                                                        dinv, rowptr, srcnorm, E);

    long nt = (long)N * HID;
    inproj_kernel<<<(N + 15) / 16, 256, 0, stream>>>(x, W_in, b_in, h, N);

    for (int i = 0; i < 3; ++i) {
        hw_kernel<<<1024, 256, 0, stream>>>(h, W_g + i * HID * HID, hw, N);
        gather_ln_kernel<<<(nt + 255) / 256, 256, 0, stream>>>(rowptr, srcnorm, hw, dinv,
                                                               b_g + i * HID, h, i > 0, N);
    }

    head_kernel<<<(nt + 255) / 256, 256, 0, stream>>>(h, Wa1, ba1, Wa2, ba2,
                                                      Wc1, bc1, Wc2, bc2, out, N);
}